// Round 10
// baseline (84.213 us; speedup 1.0000x reference)
//
#include <hip/hip_runtime.h>

// CreateInstMap: out[r,c] = 1 + argmin_k sqrt((px-cx[k])^2 + (py-cy[k])^2)
//   px = (c+1) - reg[0,r,c], py = (r+1) - reg[1,r,c]; cy=cc[k,0], cx=cc[k,1].
//
// Round 10: overlap memory with compute. R7's double-launch slope pinned the
// kernel at ~9.5us = launch(~2) + serial 16MB burst(~2.7) + compute(~2.5) +
// chains/tail — additive because 2048 blocks = full occupancy in lockstep.
// Now: 1024 blocks x 2 tiles (adjacent 32x32 tiles), ALL loads issued
// up-front in order {tileA reg, cc, tileB reg}; tileA compute proceeds at
// vmcnt(2) while tileB's 8MB streams => load(B) hides under compute(A).
//
// Candidate path (R9): wave-uniform prune mask iterated with scalar ctz in
// ascending k-order (first-index ties preserved), candidate (sx,sy,ck)
// broadcast via v_readlane. Zero LDS, zero barriers.
// Inner 6 VALU/px: fma, fma, cmp, med3(sec), min(best), cndmask(idx).
// Exactness: ref-mismatch needs earlier-index j with exact d2_j - d2_min <=
// 2^-21*d2 (rn-sqrt tie). Anchor-shifted terms <= ~2.5e5 (ulp ~0.03) =>
// g-vs-d2 pair-gap distortion <= ~0.2. End-check window
// fma(best+h, 2^-20, 1.0) = 5x margin; trip -> bit-exact __fsqrt_rn
// fallback over the same mask (~2.5% of waves). absmax has been 0 since R1.
// Prune: keep k iff d(k,anchor) <= dmin + 2R + 4 (R = measured strip
// radius; margin 4 >> 1e-2 fp error).

#define H_ 1024
#define W_ 2048
#define K_ 64
#define RELW 9.5367431640625e-7f   // 2^-20
#define ABSW 1.0f

typedef int ix4 __attribute__((ext_vector_type(4)));

__device__ __forceinline__ float readlane_f(float v, int lane) {
    return __int_as_float(__builtin_amdgcn_readlane(__float_as_int(v), lane));
}

__device__ __forceinline__ void process_tile(
    const float4 rx, const float4 ry,
    const int r, const int c, const int base,
    const float ax, const float ay,
    const float cxk, const float cyk,
    const float* __restrict__ reg, const float* __restrict__ cc,
    int* __restrict__ out)
{
    // shifted pred coords, g-coefficients, h = |p'|^2 (also radius accum)
    float pxn[4], pyn[4], h[4];
    {
        const float cshift = (float)c - ax;           // exact (int - half-int)
        const float rshift = (float)(r + 1) - ay;     // exact
        const float rv[4] = {rx.x, rx.y, rx.z, rx.w};
        const float yv[4] = {ry.x, ry.y, ry.z, ry.w};
        #pragma unroll
        for (int i = 0; i < 4; ++i) {
            const float sx = (cshift + (float)(i + 1)) - rv[i];
            const float sy = rshift - yv[i];
            pxn[i] = -2.0f * sx;                      // exact scale
            pyn[i] = -2.0f * sy;
            h[i]   = __fmaf_rn(sx, sx, sy * sy);
        }
    }
    float m = fmaxf(fmaxf(h[0], h[1]), fmaxf(h[2], h[3]));

    // per-lane center (lane == k), shifted; merged max/min shuffle reduce
    const float sxc = cxk - ax, syc = cyk - ay;
    const float ck  = __fmaf_rn(sxc, sxc, syc * syc);
    const float d   = sqrtf(ck);
    float dmin = d;
    #pragma unroll
    for (int s = 1; s < 64; s <<= 1) {
        m    = fmaxf(m,    __shfl_xor(m, s, 64));
        dmin = fminf(dmin, __shfl_xor(dmin, s, 64));
    }

    // prune: wave-uniform candidate mask
    const bool keep = d <= dmin + 2.0f * sqrtf(m) + 4.0f;
    const unsigned long long mask = __ballot(keep);

    // main loop: scalar mask iteration + readlane broadcast
    float best[4] = {INFINITY, INFINITY, INFINITY, INFINITY};
    float sec[4]  = {INFINITY, INFINITY, INFINITY, INFINITY};
    int   bidx[4] = {1, 1, 1, 1};

    unsigned long long rem = mask;
    while (rem) {
        const int lj = (int)__builtin_ctzll(rem);   // lowest k first (tie order)
        rem &= rem - 1ull;
        const float cxj = readlane_f(sxc, lj);      // wave-uniform
        const float cyj = readlane_f(syc, lj);
        const float ckj = readlane_f(ck,  lj);
        const int   kk  = lj + 1;
        #pragma unroll
        for (int i = 0; i < 4; ++i) {
            const float g = __fmaf_rn(pxn[i], cxj,
                            __fmaf_rn(pyn[i], cyj, ckj));
            const bool lt = g < best[i];
            sec[i]  = __builtin_amdgcn_fmed3f(g, best[i], sec[i]);
            best[i] = fminf(best[i], g);
            bidx[i] = lt ? kk : bidx[i];
        }
    }

    // hazard end-check: sec-best within sqrt-collision + fp-distortion window
    bool haz = false;
    #pragma unroll
    for (int i = 0; i < 4; ++i)
        haz = haz | (sec[i] - best[i] <= __fmaf_rn(best[i] + h[i], RELW, ABSW));

    // fallback (~2.5% of waves): bit-exact reference sqrt compare
    if (__any(haz)) {
        const float4 ex = *reinterpret_cast<const float4*>(reg + base);
        const float4 ey = *reinterpret_cast<const float4*>(reg + H_ * W_ + base);
        const float rv[4] = {ex.x, ex.y, ex.z, ex.w};
        const float yv[4] = {ey.x, ey.y, ey.z, ey.w};
        float px[4], py[4], sb[4];
        int bi2[4];
        const float yf = (float)(r + 1);
        #pragma unroll
        for (int i = 0; i < 4; ++i) {
            px[i] = (float)(c + i + 1) - rv[i];     // exact reference pred
            py[i] = yf - yv[i];
            sb[i] = INFINITY;
            bi2[i] = 1;
        }
        unsigned long long rem2 = mask;
        while (rem2) {
            const int lj = (int)__builtin_ctzll(rem2);
            rem2 &= rem2 - 1ull;
            const float ecy = cc[2 * lj];           // scalar loads (lj uniform)
            const float ecx = cc[2 * lj + 1];
            #pragma unroll
            for (int i = 0; i < 4; ++i) {
                const float dx = px[i] - ecx;
                const float dy = py[i] - ecy;
                const float s2 = __fsqrt_rn(__fadd_rn(__fmul_rn(dx, dx),
                                                      __fmul_rn(dy, dy)));
                const bool lt = s2 < sb[i];         // strict: first-index ties
                sb[i]  = lt ? s2 : sb[i];
                bi2[i] = lt ? (lj + 1) : bi2[i];
            }
        }
        #pragma unroll
        for (int i = 0; i < 4; ++i) bidx[i] = bi2[i];
    }

    const ix4 o = {bidx[0], bidx[1], bidx[2], bidx[3]};
    __builtin_nontemporal_store(o, reinterpret_cast<ix4*>(out + base));
}

__global__ __launch_bounds__(256) void inst_map_kernel(
    const float* __restrict__ reg,   // (2, H, W) float32
    const float* __restrict__ cc,    // (K, 2)    float32, [k] = (cy, cx)
    int* __restrict__ out)           // (H, W)    int32
{
    const int tid  = threadIdx.x;
    const int w    = tid >> 6;
    const int lane = tid & 63;

    // two adjacent 32x32 tiles per block (tile grid 64 x 32)
    const int t0 = blockIdx.x * 2;
    const int t1 = t0 + 1;
    const int tra = (t0 >> 6) * 32, tca = (t0 & 63) * 32;
    const int trb = (t1 >> 6) * 32, tcb = (t1 & 63) * 32;

    const int ro = w * 8 + (lane >> 3);       // row offset within tile
    const int co = (lane & 7) << 2;           // col offset within tile
    const int ra = tra + ro, ca = tca + co;
    const int rb = trb + ro, cb = tcb + co;
    const int basea = ra * W_ + ca;
    const int baseb = rb * W_ + cb;

    // issue ALL loads up-front, in this order: tileA, cc, tileB.
    // tileA compute then waits only vmcnt(2) while tileB streams behind it.
    const float4 rxa = *reinterpret_cast<const float4*>(reg + basea);
    const float4 rya = *reinterpret_cast<const float4*>(reg + H_ * W_ + basea);
    const float  cyk = cc[2 * lane];
    const float  cxk = cc[2 * lane + 1];
    const float4 rxb = *reinterpret_cast<const float4*>(reg + baseb);
    const float4 ryb = *reinterpret_cast<const float4*>(reg + H_ * W_ + baseb);

    process_tile(rxa, rya, ra, ca, basea,
                 (float)tca + 16.5f, (float)(tra + w * 8) + 4.5f,
                 cxk, cyk, reg, cc, out);
    process_tile(rxb, ryb, rb, cb, baseb,
                 (float)tcb + 16.5f, (float)(trb + w * 8) + 4.5f,
                 cxk, cyk, reg, cc, out);
}

extern "C" void kernel_launch(void* const* d_in, const int* in_sizes, int n_in,
                              void* d_out, int out_size, void* d_ws, size_t ws_size,
                              hipStream_t stream) {
    const float* reg = (const float*)d_in[0];   // instance_regressions (2,H,W)
    const float* cc  = (const float*)d_in[1];   // center_coords (K,2)
    int* out = (int*)d_out;                     // (H,W) int32

    inst_map_kernel<<<1024, 256, 0, stream>>>(reg, cc, out);
}

// Round 11
// 81.354 us; speedup vs baseline: 1.0351x; 1.0351x over previous
//
#include <hip/hip_runtime.h>

// CreateInstMap: out[r,c] = 1 + argmin_k sqrt((px-cx[k])^2 + (py-cy[k])^2)
//   px = (c+1) - reg[0,r,c], py = (r+1) - reg[1,r,c]; cy=cc[k,0], cx=cc[k,1].
//
// FINAL (= round-6 config, best measured: 82.68us total, absmax 0).
// Session findings (R1-R10):
//  * total = ~66us fixed harness overhead (268MB poison fills + restores)
//    + ~16us kernel; kernel floor ~6-7us (launch + mandatory 24MB HBM).
//  * Naive exact kernel: 55us, VALUBusy 81% (sqrt expansion ~26 VALU/px-k).
//  * Per-wave center pruning (64 -> ~13 candidates) + bit-exact d^2 argmin
//    with sqrt-collision hazard fallback: 55 -> ~17us. absmax 0 throughout.
//  * Further structural variants (g-form 2-FMA inner, scalar-domain
//    candidates via ballot/readlane, 8px/thread, 2-tile load overlap,
//    barrier removal beyond this version) all measured flat within +-1us —
//    residual is launch/ramp/latency at lockstep occupancy, not a pipe.
//
// Correctness structure:
//  * Per-wave prune (8x32 strip): keep k iff d(k,anchor) <= dmin + 2R + 4,
//    R = measured max strip |pred-anchor|; margin 4 >> fp error (~1e-2).
//    Pruned k provably cannot be any pixel's argmin. k-order compaction
//    preserves numpy's first-index tie semantics. No barrier: each wave
//    owns cand[w] (intra-wave lgkmcnt ordering suffices).
//  * Main loop: BIT-EXACT reference d^2 (__fmul_rn/__fadd_rn on original
//    coords, no FMA contraction), strict '<'. Only possible divergence from
//    the reference's sqrt-argmin: new d2 < best but rn(sqrt) ties (ref keeps
//    the earlier index). Equal rn(sqrt) implies (best-d2) <= 2^-21*d2; we
//    flag (best-d2) <= 2^-19*d2 (4x margin) -> fallback ~2e-6/px.
//  * Fallback: per-wave bit-exact __fsqrt_rn pass (identical rounding to
//    np.sqrt), strict '<' => bit-identical argmin.

#define H_ 1024
#define W_ 2048
#define K_ 64
#define HAZC 1.9073486e-6f   // 2^-19

typedef int ix4 __attribute__((ext_vector_type(4)));

__global__ __launch_bounds__(256) void inst_map_kernel(
    const float* __restrict__ reg,   // (2, H, W) float32
    const float* __restrict__ cc,    // (K, 2)    float32, [k] = (cy, cx)
    int* __restrict__ out)           // (H, W)    int32
{
    __shared__ float4 cand[4][K_ + 1];  // per wave: (cx, cy, kbits, 0) + pad

    const int tid  = threadIdx.x;
    const int w    = tid >> 6;               // wave id
    const int lane = tid & 63;
    const int tr0  = blockIdx.y * 32;
    const int tc0  = blockIdx.x * 32;
    const int r    = tr0 + w * 8 + (lane >> 3);   // wave strip: 8 rows x 32 cols
    const int c    = tc0 + ((lane & 7) << 2);     // 4 px/thread
    const int base = r * W_ + c;

    const float4 rx = *reinterpret_cast<const float4*>(reg + base);
    const float4 ry = *reinterpret_cast<const float4*>(reg + H_ * W_ + base);

    // exact reference pred values
    float px[4], py[4];
    const float yf = (float)(r + 1);
    px[0] = (float)(c + 1) - rx.x;  py[0] = yf - ry.x;
    px[1] = (float)(c + 2) - rx.y;  py[1] = yf - ry.y;
    px[2] = (float)(c + 3) - rx.z;  py[2] = yf - ry.z;
    px[3] = (float)(c + 4) - rx.w;  py[3] = yf - ry.w;

    // strip anchor (pixel coords 1-based); strip radius m = max |pred-a|^2
    const float ax = (float)tc0 + 16.5f;
    const float ay = (float)(tr0 + w * 8) + 4.5f;
    float m = 0.0f;
    #pragma unroll
    for (int i = 0; i < 4; ++i) {
        const float sx = px[i] - ax, sy = py[i] - ay;
        m = fmaxf(m, __fmaf_rn(sx, sx, sy * sy));
    }

    // per-lane center distance to anchor; merged max/min shuffle reduce
    const float cyk = cc[2 * lane];
    const float cxk = cc[2 * lane + 1];
    const float sxc = cxk - ax, syc = cyk - ay;
    const float d   = sqrtf(__fmaf_rn(sxc, sxc, syc * syc));
    float dmin = d;
    #pragma unroll
    for (int s = 1; s < 64; s <<= 1) {
        m    = fmaxf(m,    __shfl_xor(m, s, 64));
        dmin = fminf(dmin, __shfl_xor(dmin, s, 64));
    }

    // prune + k-order compaction into this wave's LDS region (no barrier:
    // cand[w] is written and read only by wave w; lgkmcnt orders it)
    const bool keep = d <= dmin + 2.0f * sqrtf(m) + 4.0f;
    const unsigned long long mask = __ballot(keep);
    const int ncand = (int)__popcll(mask);
    if (keep) {
        const int pos = (int)__popcll(mask & ((1ull << lane) - 1ull));
        cand[w][pos] = make_float4(cxk, cyk, __int_as_float(lane + 1), 0.0f);
    }
    if (lane == 0)   // pad: +inf coords -> d2=+inf, never wins, never hazards
        cand[w][ncand] = make_float4(INFINITY, INFINITY, __int_as_float(1), 0.0f);

    // ---- main loop: bit-exact reference d^2, strict '<', hazard flag ----
    float best[4] = {INFINITY, INFINITY, INFINITY, INFINITY};
    int   bidx[4] = {1, 1, 1, 1};
    bool  haz = false;

    float4 cd = cand[w][0];
    for (int j = 0; j < ncand; ++j) {
        const float4 nx = cand[w][j + 1];      // one-ahead prefetch (pad-safe)
        #pragma unroll
        for (int i = 0; i < 4; ++i) {
            const float dx = px[i] - cd.x;
            const float dy = py[i] - cd.y;
            const float d2 = __fadd_rn(__fmul_rn(dx, dx), __fmul_rn(dy, dy));
            const bool lt = d2 < best[i];
            // sqrt-collision hazard: lt but rn(sqrt) could tie with best
            haz = haz | (lt & (best[i] - d2 <= __fmul_rn(d2, HAZC)));
            best[i] = lt ? d2 : best[i];
            bidx[i] = lt ? __float_as_int(cd.z) : bidx[i];
        }
        cd = nx;
    }

    // ---- fallback (~few px per image): bit-exact sqrt compare ----
    if (__any(haz)) {
        float sb[4]  = {INFINITY, INFINITY, INFINITY, INFINITY};
        int   bi2[4] = {1, 1, 1, 1};
        for (int j = 0; j < ncand; ++j) {
            const float4 c2 = cand[w][j];
            const int kk = __float_as_int(c2.z);
            const float ecy = cc[2 * (kk - 1)];       // exact coords
            const float ecx = cc[2 * (kk - 1) + 1];
            #pragma unroll
            for (int i = 0; i < 4; ++i) {
                const float dx = px[i] - ecx;
                const float dy = py[i] - ecy;
                const float s2 = __fsqrt_rn(__fadd_rn(__fmul_rn(dx, dx),
                                                      __fmul_rn(dy, dy)));
                const bool lt = s2 < sb[i];           // strict: first-index ties
                sb[i]  = lt ? s2 : sb[i];
                bi2[i] = lt ? kk : bi2[i];
            }
        }
        #pragma unroll
        for (int i = 0; i < 4; ++i) bidx[i] = bi2[i];
    }

    const ix4 o = {bidx[0], bidx[1], bidx[2], bidx[3]};
    __builtin_nontemporal_store(o, reinterpret_cast<ix4*>(out + base));
}

extern "C" void kernel_launch(void* const* d_in, const int* in_sizes, int n_in,
                              void* d_out, int out_size, void* d_ws, size_t ws_size,
                              hipStream_t stream) {
    const float* reg = (const float*)d_in[0];   // instance_regressions (2,H,W)
    const float* cc  = (const float*)d_in[1];   // center_coords (K,2)
    int* out = (int*)d_out;                     // (H,W) int32

    dim3 grid(W_ / 32, H_ / 32);                // (64, 32) = 2048 blocks
    inst_map_kernel<<<grid, 256, 0, stream>>>(reg, cc, out);
}